// Round 1
// baseline (343.387 us; speedup 1.0000x reference)
//
#include <hip/hip_runtime.h>

#define NB 2048
#define SEQ 200
#define DIM 64
#define NH1 64
#define NH2 16
#define EPSF 1e-9f
#define CHUNK 64

__global__ __launch_bounds__(256, 4)
void din_attn_kernel(const float* __restrict__ q,        // [B,64]
                     const float* __restrict__ key,      // [B,200,64]
                     const int*   __restrict__ seqlen,   // [B,1]
                     const float* __restrict__ W1,       // [256,64]
                     const float* __restrict__ alpha1v,
                     const float* __restrict__ mean1v,
                     const float* __restrict__ var1v,
                     const float* __restrict__ W2,       // [64,16]
                     const float* __restrict__ alpha2v,
                     const float* __restrict__ mean2v,
                     const float* __restrict__ var2v,
                     const float* __restrict__ W3,       // [16]
                     float* __restrict__ out)            // [B,64]
{
    __shared__ float wc_tile[DIM][NH1];      // 16 KB  combined weight staging
    __shared__ float qterm_part[4][NH1];     // 1 KB
    __shared__ float h1t[CHUNK][NH1 + 1];    // 16.25 KB (pad avoids bank conflicts)
    __shared__ float wrow[CHUNK];
    __shared__ float scorep[4][CHUNK];
    __shared__ float outp[4][DIM];

    const int b    = blockIdx.x;
    const int t    = threadIdx.x;
    const int lane = t & 63;
    const int wave = __builtin_amdgcn_readfirstlane(t >> 6);

    const float* qrow = q + (size_t)b * DIM;     // wave-uniform pointer
    int nseq = seqlen[b];                        // uniform scalar load
    nseq = nseq < SEQ ? nseq : SEQ;

    // ---- setup: Wc[d][h] = (W1b - W1c)[d][h] + q[d]*W1d[d][h];
    //             qterm[h] = sum_d q[d]*(W1a + W1c)[d][h]
    {
        const int h = lane;
        float qt = 0.f;
        #pragma unroll
        for (int i = 0; i < 16; ++i) {
            const int d = wave * 16 + i;           // uniform
            const float qd  = qrow[d];             // uniform -> sgpr
            const float w1a = W1[(d)       * NH1 + h];
            const float w1b = W1[(64 + d)  * NH1 + h];
            const float w1c = W1[(128 + d) * NH1 + h];
            const float w1d = W1[(192 + d) * NH1 + h];
            wc_tile[d][h] = (w1b - w1c) + qd * w1d;
            qt = fmaf(qd, w1a + w1c, qt);
        }
        qterm_part[wave][h] = qt;
    }
    __syncthreads();

    // per-lane layer-1 params (lane = h)
    const float a1 = alpha1v[lane];
    const float m1 = mean1v[lane];
    const float r1 = rsqrtf(var1v[lane] + EPSF);

    // per-wave layer-2 params (j = wave*4 + jj, wave-uniform -> sgpr)
    float a2[4], m2[4], r2[4], w3[4];
    #pragma unroll
    for (int jj = 0; jj < 4; ++jj) {
        const int j = wave * 4 + jj;
        a2[jj] = alpha2v[j];
        m2[jj] = mean2v[j];
        r2[jj] = rsqrtf(var2v[j] + EPSF);
        w3[jj] = W3[j];
    }

    // pull Wc into registers (lane = h); qterm reduce
    float wc[DIM];
    float qterm;
    {
        #pragma unroll
        for (int d = 0; d < DIM; ++d) wc[d] = wc_tile[d][lane];
        qterm = (qterm_part[0][lane] + qterm_part[1][lane]) +
                (qterm_part[2][lane] + qterm_part[3][lane]);
    }
    __syncthreads();

    float oacc = 0.f;   // output partial, lane = d

    for (int base = 0; base < SEQ; base += CHUNK) {
        if (base >= nseq) break;                       // uniform branch
        const int vrows = min(CHUNK, nseq - base);     // valid rows this chunk

        // ---- phase 1: h1 = dice1(qterm + k @ Wc); lane = h, waves stride rows
        for (int i = 0; i < 16; ++i) {
            const int sl = wave + 4 * i;               // uniform within wave
            if (sl >= vrows) break;
            const float* krow = key + ((size_t)b * SEQ + base + sl) * DIM; // uniform
            float acc0 = qterm, acc1 = 0.f, acc2 = 0.f, acc3 = 0.f;
            #pragma unroll
            for (int d = 0; d < DIM; d += 4) {
                acc0 = fmaf(krow[d + 0], wc[d + 0], acc0);
                acc1 = fmaf(krow[d + 1], wc[d + 1], acc1);
                acc2 = fmaf(krow[d + 2], wc[d + 2], acc2);
                acc3 = fmaf(krow[d + 3], wc[d + 3], acc3);
            }
            const float x  = (acc0 + acc1) + (acc2 + acc3);
            const float xn = (x - m1) * r1;
            const float p  = 1.f / (1.f + __expf(-xn));
            h1t[sl][lane] = x * (a1 + p * (1.f - a1));
        }
        __syncthreads();

        // ---- phase 2: h2 = dice2(h1 @ W2); score = h2 @ W3. lane = s_local.
        {
            const int sl = lane;
            float h2acc[4] = {0.f, 0.f, 0.f, 0.f};
            #pragma unroll
            for (int h = 0; h < NH1; ++h) {
                const float hv = h1t[sl][h];
                #pragma unroll
                for (int jj = 0; jj < 4; ++jj)
                    h2acc[jj] = fmaf(hv, W2[h * NH2 + wave * 4 + jj], h2acc[jj]);
            }
            float sc = 0.f;
            #pragma unroll
            for (int jj = 0; jj < 4; ++jj) {
                const float x  = h2acc[jj];
                const float xn = (x - m2[jj]) * r2[jj];
                const float p  = 1.f / (1.f + __expf(-xn));
                const float hd = x * (a2[jj] + p * (1.f - a2[jj]));
                sc = fmaf(hd, w3[jj], sc);
            }
            scorep[wave][sl] = sc;
        }
        __syncthreads();

        // ---- score reduce + sigmoid -> weights
        if (t < CHUNK) {
            const float s4 = (scorep[0][t] + scorep[1][t]) +
                             (scorep[2][t] + scorep[3][t]);
            wrow[t] = 1.f / (1.f + __expf(-s4));
        }
        __syncthreads();

        // ---- phase 3: out[d] += w_s * k[s][d]; lane = d, waves stride rows
        for (int i = 0; i < 16; ++i) {
            const int sl = wave + 4 * i;
            if (sl >= vrows) break;
            const float w = wrow[sl];                  // LDS broadcast
            const float* krow = key + ((size_t)b * SEQ + base + sl) * DIM;
            oacc = fmaf(w, krow[lane], oacc);          // coalesced vector load
        }
        __syncthreads();   // h1t/wrow reused next chunk
    }

    // ---- cross-wave output reduction
    outp[wave][lane] = oacc;
    __syncthreads();
    if (t < DIM) {
        out[(size_t)b * DIM + t] = (outp[0][t] + outp[1][t]) +
                                   (outp[2][t] + outp[3][t]);
    }
}

extern "C" void kernel_launch(void* const* d_in, const int* in_sizes, int n_in,
                              void* d_out, int out_size, void* d_ws, size_t ws_size,
                              hipStream_t stream) {
    const float* q      = (const float*)d_in[0];
    const float* key    = (const float*)d_in[1];
    const int*   seqlen = (const int*)d_in[2];
    const float* W1     = (const float*)d_in[3];
    const float* alpha1 = (const float*)d_in[4];
    const float* mean1  = (const float*)d_in[5];
    const float* var1   = (const float*)d_in[6];
    const float* W2     = (const float*)d_in[7];
    const float* alpha2 = (const float*)d_in[8];
    const float* mean2  = (const float*)d_in[9];
    const float* var2   = (const float*)d_in[10];
    const float* W3     = (const float*)d_in[11];
    float* out          = (float*)d_out;

    din_attn_kernel<<<NB, 256, 0, stream>>>(q, key, seqlen, W1,
                                            alpha1, mean1, var1,
                                            W2, alpha2, mean2, var2,
                                            W3, out);
}

// Round 2
// 184.117 us; speedup vs baseline: 1.8650x; 1.8650x over previous
//
#include <hip/hip_runtime.h>

#define NB   2048
#define SEQ  200
#define DIM  64
#define NH1  64
#define NH2  16
#define EPSF 1e-9f
#define CHUNK 64

typedef float fvec4 __attribute__((ext_vector_type(4)));
typedef short svec8 __attribute__((ext_vector_type(8)));   // 8 bf16 = 4 VGPRs

// LDS layout (bytes). wc_tile (setup, 16 KB) overlaps kfrag+h1frag;
// qterm_part (setup) overlaps outp (epilogue).
#define KFRAG_OFF  0        // 8192 B : k chunk, bf16, A-frag swizzled
#define H1FRAG_OFF 8192     // 8192 B : h1, bf16, A-frag swizzled
#define WROW_OFF   16384    // 256 B  : weights
#define QALL_OFF   16640    // 256 B  : qterm[64]
#define OUTP_OFF   16896    // 1024 B : cross-wave out partials
#define SMEM_BYTES 17920

__device__ __forceinline__ short f2bf(float f) {
    unsigned u = __float_as_uint(f);
    u += 0x7fffu + ((u >> 16) & 1u);      // round-to-nearest-even
    return (short)(u >> 16);
}

__global__ __launch_bounds__(256, 4)
void din_attn_kernel(const float* __restrict__ q,        // [B,64]
                     const float* __restrict__ key,      // [B,200,64]
                     const int*   __restrict__ seqlen,   // [B,1]
                     const float* __restrict__ W1,       // [256,64]
                     const float* __restrict__ alpha1v,
                     const float* __restrict__ mean1v,
                     const float* __restrict__ var1v,
                     const float* __restrict__ W2,       // [64,16]
                     const float* __restrict__ alpha2v,
                     const float* __restrict__ mean2v,
                     const float* __restrict__ var2v,
                     const float* __restrict__ W3,       // [16]
                     float* __restrict__ out)            // [B,64]
{
    __shared__ __align__(16) char smem[SMEM_BYTES];
    float* wc_t  = (float*)(smem);            // [64 d][64 h] setup only
    char*  kfrag = smem + KFRAG_OFF;
    char*  h1f   = smem + H1FRAG_OFF;
    float* wrowf = (float*)(smem + WROW_OFF);
    float* qall  = (float*)(smem + QALL_OFF);
    float* outp  = (float*)(smem + OUTP_OFF);
    float* qpart = (float*)(smem + OUTP_OFF); // setup alias

    const int b    = blockIdx.x;
    const int t    = threadIdx.x;
    const int lane = t & 63;
    const int wave = __builtin_amdgcn_readfirstlane(t >> 6);
    const int qd4  = lane >> 4;     // quad 0..3
    const int m    = lane & 15;

    const float* qrow = q + (size_t)b * DIM;
    int nseq = seqlen[b];
    nseq = nseq < SEQ ? nseq : SEQ;

    // ---- setup 1: wc_t[d][h] = (W1b - W1c) + q[d]*W1d ; qterm partials
    {
        const int h = lane;
        float qt = 0.f;
        #pragma unroll
        for (int i = 0; i < 16; ++i) {
            const int d = wave * 16 + i;
            const float qdv = qrow[d];
            const float w1a = W1[(d)       * NH1 + h];
            const float w1b = W1[(64 + d)  * NH1 + h];
            const float w1c = W1[(128 + d) * NH1 + h];
            const float w1dd= W1[(192 + d) * NH1 + h];
            wc_t[d * NH1 + h] = (w1b - w1c) + qdv * w1dd;
            qt = fmaf(qdv, w1a + w1c, qt);
        }
        qpart[wave * 64 + h] = qt;
    }
    __syncthreads();

    // ---- setup 2: qterm reduce; B-fragments (Wc, W2) to registers; params
    if (t < 64)
        qall[t] = (qpart[t] + qpart[64 + t]) + (qpart[128 + t] + qpart[192 + t]);

    svec8 wcf[4][2];   // Wc B-frags: [colblock c][kstep kk]
    #pragma unroll
    for (int c = 0; c < 4; ++c)
        #pragma unroll
        for (int kk = 0; kk < 2; ++kk) {
            svec8 f;
            #pragma unroll
            for (int j = 0; j < 8; ++j) {
                const int d = kk * 32 + qd4 * 8 + j;
                f[j] = f2bf(wc_t[d * NH1 + (c * 16 + m)]);
            }
            wcf[c][kk] = f;
        }

    svec8 w2f[2];      // W2 B-frags
    #pragma unroll
    for (int kk = 0; kk < 2; ++kk) {
        svec8 f;
        #pragma unroll
        for (int j = 0; j < 8; ++j) {
            const int h = kk * 32 + qd4 * 8 + j;
            f[j] = f2bf(W2[h * NH2 + m]);
        }
        w2f[kk] = f;
    }

    // dice1 params for h = c*16 + m
    float a1v[4], m1v[4], r1v[4];
    #pragma unroll
    for (int c = 0; c < 4; ++c) {
        a1v[c] = alpha1v[c * 16 + m];
        m1v[c] = mean1v[c * 16 + m];
        r1v[c] = rsqrtf(var1v[c * 16 + m] + EPSF);
    }
    // dice2 params for j = m
    const float a2s = alpha2v[m];
    const float m2s = mean2v[m];
    const float r2s = rsqrtf(var2v[m] + EPSF);
    const float w3s = W3[m];

    __syncthreads();   // wc_t -> kfrag reuse; qall ready

    float qtermv[4];
    #pragma unroll
    for (int c = 0; c < 4; ++c) qtermv[c] = qall[c * 16 + m];

    float oacc = 0.f;  // lane = d output partial

    for (int base = 0; base < SEQ; base += CHUNK) {
        if (base >= nseq) break;                     // uniform
        const int vrows = min(CHUNK, nseq - base);

        // ---- stage k chunk -> bf16 A-frag layout in LDS
        #pragma unroll
        for (int iter = 0; iter < 4; ++iter) {
            const int F    = iter * 256 + t;         // float4 index 0..1023
            const int m64  = F >> 4;                 // chunk row 0..63
            const int c4   = (F & 15) * 4;           // col 0..60
            int grow = base + m64;
            grow = grow < SEQ ? grow : SEQ - 1;      // clamp (garbage rows masked)
            const float* src = key + ((size_t)b * SEQ + grow) * DIM + c4;
            const float v0 = src[0], v1 = src[1], v2 = src[2], v3 = src[3];
            unsigned p0 = (unsigned short)f2bf(v0) | ((unsigned)(unsigned short)f2bf(v1) << 16);
            unsigned p1 = (unsigned short)f2bf(v2) | ((unsigned)(unsigned short)f2bf(v3) << 16);
            const int r  = m64 >> 4;
            const int kk = c4 >> 5;
            const int qq = (c4 & 31) >> 3;
            const int ln = qq * 16 + (m64 & 15);
            uint2 pk; pk.x = p0; pk.y = p1;
            *(uint2*)(kfrag + (((r << 1) + kk) << 10) + (ln << 4) + ((c4 & 7) << 1)) = pk;
        }
        __syncthreads();

        // ---- phase 1: x = k @ Wc via MFMA (wave owns row block r = wave)
        const svec8 a0 = *(const svec8*)(kfrag + (((wave << 1) + 0) << 10) + (lane << 4));
        const svec8 a1 = *(const svec8*)(kfrag + (((wave << 1) + 1) << 10) + (lane << 4));
        fvec4 acc[4];
        #pragma unroll
        for (int c = 0; c < 4; ++c) {
            acc[c] = (fvec4){0.f, 0.f, 0.f, 0.f};
            acc[c] = __builtin_amdgcn_mfma_f32_16x16x32_bf16(a0, wcf[c][0], acc[c], 0, 0, 0);
            acc[c] = __builtin_amdgcn_mfma_f32_16x16x32_bf16(a1, wcf[c][1], acc[c], 0, 0, 0);
        }

        // ---- dice1 epilogue; write h1 (bf16) in phase-2 A-frag layout
        #pragma unroll
        for (int c = 0; c < 4; ++c) {
            const int kk2 = c >> 1;
            const int qhi = (c & 1) * 2 + (m >> 3);
            #pragma unroll
            for (int reg = 0; reg < 4; ++reg) {
                const float x  = acc[c][reg] + qtermv[c];
                const float xn = (x - m1v[c]) * r1v[c];
                const float p  = 1.f / (1.f + __expf(-xn));
                const float h1 = x * (a1v[c] + p * (1.f - a1v[c]));
                const int l2 = qhi * 16 + (qd4 * 4 + reg);
                *(short*)(h1f + (((wave << 1) + kk2) << 10) + (l2 << 4) + ((m & 7) << 1))
                    = f2bf(h1);
            }
        }
        // same-wave write->read of h1f region; no barrier needed

        // ---- phase 2: h2 = h1 @ W2 via MFMA; dice2; score; weights
        {
            const svec8 b0 = *(const svec8*)(h1f + (((wave << 1) + 0) << 10) + (lane << 4));
            const svec8 b1 = *(const svec8*)(h1f + (((wave << 1) + 1) << 10) + (lane << 4));
            fvec4 acc2 = (fvec4){0.f, 0.f, 0.f, 0.f};
            acc2 = __builtin_amdgcn_mfma_f32_16x16x32_bf16(b0, w2f[0], acc2, 0, 0, 0);
            acc2 = __builtin_amdgcn_mfma_f32_16x16x32_bf16(b1, w2f[1], acc2, 0, 0, 0);
            #pragma unroll
            for (int reg = 0; reg < 4; ++reg) {
                const float x  = acc2[reg];                 // h2[sl][j=m]
                const float xn = (x - m2s) * r2s;
                const float p  = 1.f / (1.f + __expf(-xn));
                const float hd = x * (a2s + p * (1.f - a2s));
                float s = hd * w3s;                         // partial over j
                s += __shfl_xor(s, 1);
                s += __shfl_xor(s, 2);
                s += __shfl_xor(s, 4);
                s += __shfl_xor(s, 8);                      // sum over 16 j-lanes
                const int sl = wave * 16 + qd4 * 4 + reg;
                if (m == 0)
                    wrowf[sl] = (sl < vrows) ? 1.f / (1.f + __expf(-s)) : 0.f;
            }
        }
        __syncthreads();   // wrow ready for all waves

        // ---- phase 3: out[d] += w_s * k[s][d]; lane = d (L1-hot re-read)
        #pragma unroll
        for (int i = 0; i < 16; ++i) {
            const int sl = wave + 4 * i;
            int grow = base + sl;
            grow = grow < SEQ ? grow : SEQ - 1;
            const float w = wrowf[sl];                     // 0 for invalid rows
            const float* krow = key + ((size_t)b * SEQ + grow) * DIM;
            oacc = fmaf(w, krow[lane], oacc);
        }
        // next chunk's staging writes are fenced by its own post-staging barrier
    }

    // ---- cross-wave output reduction
    outp[wave * 64 + lane] = oacc;
    __syncthreads();
    if (t < 64) {
        out[(size_t)b * DIM + t] = (outp[t] + outp[64 + t]) +
                                   (outp[128 + t] + outp[192 + t]);
    }
}

extern "C" void kernel_launch(void* const* d_in, const int* in_sizes, int n_in,
                              void* d_out, int out_size, void* d_ws, size_t ws_size,
                              hipStream_t stream) {
    const float* q      = (const float*)d_in[0];
    const float* key    = (const float*)d_in[1];
    const int*   seqlen = (const int*)d_in[2];
    const float* W1     = (const float*)d_in[3];
    const float* alpha1 = (const float*)d_in[4];
    const float* mean1  = (const float*)d_in[5];
    const float* var1   = (const float*)d_in[6];
    const float* W2     = (const float*)d_in[7];
    const float* alpha2 = (const float*)d_in[8];
    const float* mean2  = (const float*)d_in[9];
    const float* var2   = (const float*)d_in[10];
    const float* W3     = (const float*)d_in[11];
    float* out          = (float*)d_out;

    din_attn_kernel<<<NB, 256, 0, stream>>>(q, key, seqlen, W1,
                                            alpha1, mean1, var1,
                                            W2, alpha2, mean2, var2,
                                            W3, out);
}